// Round 1
// baseline (110.477 us; speedup 1.0000x reference)
//
#include <hip/hip_runtime.h>
#include <hip/hip_bf16.h>

#define B_ 16
#define T_ 4096
#define C_ 1024
#define TP2 (T_ + 2)

// One block per output row (b, t). 256 threads, 4 floats/thread (float4).
__global__ __launch_bounds__(256) void embed_ln_kernel(
    const float* __restrict__ x,         // (B, T, C)
    const int*   __restrict__ lengths,   // (B,)
    const float* __restrict__ bos,       // (C,)
    const float* __restrict__ eos,       // (C,)
    const float* __restrict__ pos_table, // (8194, C)
    const float* __restrict__ ln_w,      // (C,)
    const float* __restrict__ ln_b,      // (C,)
    float* __restrict__ out_y,           // (B, T+2, C)
    float* __restrict__ out_mask,        // (B, T+2) as float 0/1
    float* __restrict__ out_len)         // (B,) as float
{
    const int row = blockIdx.x;          // 0 .. B*(T+2)-1
    const int b   = row / TP2;
    const int t   = row - b * TP2;
    const int L   = lengths[b];
    const int tid = threadIdx.x;

    // ---- gather the source row ----
    float4 v;
    if (t == 0) {
        v = reinterpret_cast<const float4*>(bos)[tid];
    } else if (t == L + 1) {
        v = reinterpret_cast<const float4*>(eos)[tid];
    } else if (t <= T_) {
        const float* src = x + (size_t)(b * T_ + (t - 1)) * C_;
        v = reinterpret_cast<const float4*>(src)[tid];
    } else {
        v = make_float4(0.f, 0.f, 0.f, 0.f);
    }

    // ---- add positional embedding (non-pad slots only) ----
    if (t <= L + 1) {
        const float* pr = pos_table + (size_t)(t + 2) * C_;
        float4 p = reinterpret_cast<const float4*>(pr)[tid];
        v.x += p.x; v.y += p.y; v.z += p.z; v.w += p.w;
    }

    // ---- block reduction for mean / variance ----
    float s  = v.x + v.y + v.z + v.w;
    float ss = v.x * v.x + v.y * v.y + v.z * v.z + v.w * v.w;
    #pragma unroll
    for (int off = 32; off > 0; off >>= 1) {
        s  += __shfl_down(s,  off);
        ss += __shfl_down(ss, off);
    }
    __shared__ float sh_s[4], sh_ss[4];
    const int wave = tid >> 6;
    if ((tid & 63) == 0) { sh_s[wave] = s; sh_ss[wave] = ss; }
    __syncthreads();
    const float tot  = sh_s[0] + sh_s[1] + sh_s[2] + sh_s[3];
    const float tot2 = sh_ss[0] + sh_ss[1] + sh_ss[2] + sh_ss[3];
    const float inv_c = 1.0f / (float)C_;
    const float mu   = tot * inv_c;
    const float var  = tot2 * inv_c - mu * mu;
    const float rstd = rsqrtf(var + 1e-5f);

    // ---- normalize, scale, shift, store ----
    const float4 w  = reinterpret_cast<const float4*>(ln_w)[tid];
    const float4 bb = reinterpret_cast<const float4*>(ln_b)[tid];
    float4 o;
    o.x = (v.x - mu) * rstd * w.x + bb.x;
    o.y = (v.y - mu) * rstd * w.y + bb.y;
    o.z = (v.z - mu) * rstd * w.z + bb.z;
    o.w = (v.w - mu) * rstd * w.w + bb.w;
    reinterpret_cast<float4*>(out_y + (size_t)row * C_)[tid] = o;

    // ---- auxiliary outputs ----
    if (tid == 0) {
        out_mask[row] = (t >= L + 2) ? 1.0f : 0.0f;
        if (t == 0) out_len[b] = (float)(L + 2);
    }
}

extern "C" void kernel_launch(void* const* d_in, const int* in_sizes, int n_in,
                              void* d_out, int out_size, void* d_ws, size_t ws_size,
                              hipStream_t stream) {
    const float* x         = (const float*)d_in[0];
    // d_in[1] = padding_mask (unused; recomputed from lengths)
    const int*   lengths   = (const int*)d_in[2];
    const float* bos       = (const float*)d_in[3];
    const float* eos       = (const float*)d_in[4];
    const float* pos_table = (const float*)d_in[5];
    const float* ln_w      = (const float*)d_in[6];
    const float* ln_b      = (const float*)d_in[7];

    float* out_y    = (float*)d_out;
    float* out_mask = out_y + (size_t)B_ * TP2 * C_;
    float* out_len  = out_mask + (size_t)B_ * TP2;

    const int grid = B_ * TP2;  // 65568 rows
    embed_ln_kernel<<<grid, 256, 0, stream>>>(
        x, lengths, bos, eos, pos_table, ln_w, ln_b,
        out_y, out_mask, out_len);
}

// Round 4
// 102.827 us; speedup vs baseline: 1.0744x; 1.0744x over previous
//
#include <hip/hip_runtime.h>
#include <hip/hip_bf16.h>

#define B_ 16
#define T_ 4096
#define C_ 1024
#define TP2 (T_ + 2)
#define NROWS (B_ * TP2)   // 65568, divisible by 4

typedef float float4v __attribute__((ext_vector_type(4)));

// One WAVE per output row (4 rows per 256-thread block).
// Each lane owns 4 float4 chunks: chunk i at float4-index i*64+lane.
// No LDS, no __syncthreads — reduction is a 64-lane shfl_xor butterfly.
__global__ __launch_bounds__(256) void embed_ln_kernel(
    const float* __restrict__ x,         // (B, T, C)
    const int*   __restrict__ lengths,   // (B,)
    const float* __restrict__ bos,       // (C,)
    const float* __restrict__ eos,       // (C,)
    const float* __restrict__ pos_table, // (8194, C)
    const float* __restrict__ ln_w,      // (C,)
    const float* __restrict__ ln_b,      // (C,)
    float* __restrict__ out_y,           // (B, T+2, C)
    float* __restrict__ out_mask,        // (B, T+2) as float 0/1
    float* __restrict__ out_len)         // (B,) as float
{
    const int row  = blockIdx.x * 4 + (threadIdx.x >> 6);  // 0 .. NROWS-1
    const int lane = threadIdx.x & 63;
    const int b    = row / TP2;
    const int t    = row - b * TP2;
    const int L    = lengths[b];

    // ---- gather the source row (streaming: nontemporal) ----
    float4v v[4];
    const float4v* srcv = nullptr;
    if (t == 0)          srcv = reinterpret_cast<const float4v*>(bos);
    else if (t == L + 1) srcv = reinterpret_cast<const float4v*>(eos);
    else if (t <= T_)    srcv = reinterpret_cast<const float4v*>(
                                    x + (size_t)(b * T_ + (t - 1)) * C_);
    if (srcv) {
        #pragma unroll
        for (int i = 0; i < 4; ++i)
            v[i] = __builtin_nontemporal_load(&srcv[i * 64 + lane]);
    } else {
        #pragma unroll
        for (int i = 0; i < 4; ++i)
            v[i] = (float4v)(0.f);
    }

    // ---- add positional embedding (non-pad slots only; cached — reused 16x) ----
    if (t <= L + 1) {
        const float4v* pr = reinterpret_cast<const float4v*>(
                                pos_table + (size_t)(t + 2) * C_);
        #pragma unroll
        for (int i = 0; i < 4; ++i)
            v[i] += pr[i * 64 + lane];
    }

    // ---- wave-level mean/var reduction (no LDS, no barrier) ----
    float s = 0.f, ss = 0.f;
    #pragma unroll
    for (int i = 0; i < 4; ++i) {
        s  += v[i].x + v[i].y + v[i].z + v[i].w;
        ss += v[i].x * v[i].x + v[i].y * v[i].y
            + v[i].z * v[i].z + v[i].w * v[i].w;
    }
    #pragma unroll
    for (int off = 32; off > 0; off >>= 1) {
        s  += __shfl_xor(s,  off);
        ss += __shfl_xor(ss, off);
    }
    const float inv_c = 1.0f / (float)C_;
    const float mu    = s * inv_c;
    const float var   = ss * inv_c - mu * mu;
    const float rstd  = rsqrtf(var + 1e-5f);

    // ---- normalize, scale, shift, store (streaming store) ----
    float4v* dst = reinterpret_cast<float4v*>(out_y + (size_t)row * C_);
    const float4v* wv = reinterpret_cast<const float4v*>(ln_w);
    const float4v* bv = reinterpret_cast<const float4v*>(ln_b);
    #pragma unroll
    for (int i = 0; i < 4; ++i) {
        const float4v w  = wv[i * 64 + lane];
        const float4v bb = bv[i * 64 + lane];
        float4v o = (v[i] - mu) * rstd * w + bb;
        __builtin_nontemporal_store(o, &dst[i * 64 + lane]);
    }

    // ---- auxiliary outputs ----
    if (lane == 0) {
        out_mask[row] = (t >= L + 2) ? 1.0f : 0.0f;
        if (t == 0) out_len[b] = (float)(L + 2);
    }
}

extern "C" void kernel_launch(void* const* d_in, const int* in_sizes, int n_in,
                              void* d_out, int out_size, void* d_ws, size_t ws_size,
                              hipStream_t stream) {
    const float* x         = (const float*)d_in[0];
    // d_in[1] = padding_mask (unused; recomputed from lengths)
    const int*   lengths   = (const int*)d_in[2];
    const float* bos       = (const float*)d_in[3];
    const float* eos       = (const float*)d_in[4];
    const float* pos_table = (const float*)d_in[5];
    const float* ln_w      = (const float*)d_in[6];
    const float* ln_b      = (const float*)d_in[7];

    float* out_y    = (float*)d_out;
    float* out_mask = out_y + (size_t)B_ * TP2 * C_;
    float* out_len  = out_mask + (size_t)B_ * TP2;

    const int grid = NROWS / 4;  // 16392 blocks, 1 wave per row
    embed_ln_kernel<<<grid, 256, 0, stream>>>(
        x, lengths, bos, eos, pos_table, ln_w, ln_b,
        out_y, out_mask, out_len);
}

// Round 5
// 101.699 us; speedup vs baseline: 1.0863x; 1.0111x over previous
//
#include <hip/hip_runtime.h>
#include <hip/hip_bf16.h>

#define B_ 16
#define T_ 4096
#define C_ 1024
#define TP2 (T_ + 2)
#define BPW 4                      // batches per wave
#define NGRP (B_ / BPW)            // 4 groups
#define NWAVES (TP2 * NGRP)        // 16392
#define NBLK (NWAVES / 4)          // 4098 blocks of 256 (4 waves)

typedef float float4v __attribute__((ext_vector_type(4)));

// t-major: one wave owns a single t and 4 batches.
// pos[t+2], ln_w, ln_b hoisted into registers once per wave;
// 2-deep software pipeline over the 4 batch rows (static buffer indices).
__global__ __launch_bounds__(256) void embed_ln_kernel(
    const float* __restrict__ x,         // (B, T, C)
    const int*   __restrict__ lengths,   // (B,)
    const float* __restrict__ bos,       // (C,)
    const float* __restrict__ eos,       // (C,)
    const float* __restrict__ pos_table, // (8194, C)
    const float* __restrict__ ln_w,      // (C,)
    const float* __restrict__ ln_b,      // (C,)
    float* __restrict__ out_y,           // (B, T+2, C)
    float* __restrict__ out_mask,        // (B, T+2) as float 0/1
    float* __restrict__ out_len)         // (B,) as float
{
    const int wid  = blockIdx.x * 4 + (threadIdx.x >> 6);  // 0..NWAVES-1
    const int lane = threadIdx.x & 63;
    const int t    = wid >> 2;           // 0..4097
    const int b0   = (wid & 3) * BPW;    // 0,4,8,12

    // ---- hoisted wave-invariants: ln_w, ln_b, pos row (t+2 <= 4099 < 8194) ----
    float4v w[4], bb[4], ps[4];
    {
        const float4v* wv = reinterpret_cast<const float4v*>(ln_w);
        const float4v* bv = reinterpret_cast<const float4v*>(ln_b);
        const float4v* pv = reinterpret_cast<const float4v*>(
                                pos_table + (size_t)(t + 2) * C_);
        #pragma unroll
        for (int i = 0; i < 4; ++i) {
            w[i]  = wv[i * 64 + lane];
            bb[i] = bv[i * 64 + lane];
            ps[i] = pv[i * 64 + lane];
        }
    }

    int L4[BPW];
    #pragma unroll
    for (int j = 0; j < BPW; ++j) L4[j] = lengths[b0 + j];

    // source row pointer for batch j at this t (nullptr => zero row, t==T+1)
    auto src_of = [&](int j) -> const float4v* {
        if (t == 0)         return reinterpret_cast<const float4v*>(bos);
        if (t == L4[j] + 1) return reinterpret_cast<const float4v*>(eos);
        if (t <= T_)        return reinterpret_cast<const float4v*>(
                                x + (size_t)((b0 + j) * T_ + (t - 1)) * C_);
        return nullptr;
    };

    auto loadrow = [&](float4v (&buf)[4], const float4v* sp) {
        if (sp) {
            #pragma unroll
            for (int i = 0; i < 4; ++i)
                buf[i] = __builtin_nontemporal_load(&sp[i * 64 + lane]);
        } else {
            #pragma unroll
            for (int i = 0; i < 4; ++i) buf[i] = (float4v)(0.f);
        }
    };

    auto process = [&](float4v (&v)[4], int j) {
        const int L = L4[j];
        if (t <= L + 1) {
            #pragma unroll
            for (int i = 0; i < 4; ++i) v[i] += ps[i];
        }
        float s = 0.f, ss = 0.f;
        #pragma unroll
        for (int i = 0; i < 4; ++i) {
            s  += v[i].x + v[i].y + v[i].z + v[i].w;
            ss += v[i].x * v[i].x + v[i].y * v[i].y
                + v[i].z * v[i].z + v[i].w * v[i].w;
        }
        #pragma unroll
        for (int off = 32; off > 0; off >>= 1) {
            s  += __shfl_xor(s,  off);
            ss += __shfl_xor(ss, off);
        }
        const float inv_c = 1.0f / (float)C_;
        const float mu   = s * inv_c;
        const float var  = ss * inv_c - mu * mu;
        const float rstd = rsqrtf(var + 1e-5f);
        const int row = (b0 + j) * TP2 + t;
        float4v* dst = reinterpret_cast<float4v*>(out_y + (size_t)row * C_);
        #pragma unroll
        for (int i = 0; i < 4; ++i) {
            float4v o = (v[i] - mu) * rstd * w[i] + bb[i];
            __builtin_nontemporal_store(o, &dst[i * 64 + lane]);
        }
        if (lane == 0) {
            out_mask[row] = (t >= L + 2) ? 1.0f : 0.0f;
            if (t == 0) out_len[b0 + j] = (float)(L + 2);
        }
    };

    // ---- 2-deep pipeline over 4 batch rows (all indices static) ----
    float4v va[4], vb[4];
    loadrow(va, src_of(0));
    loadrow(vb, src_of(1));
    process(va, 0);
    loadrow(va, src_of(2));
    process(vb, 1);
    loadrow(vb, src_of(3));
    process(va, 2);
    process(vb, 3);
}

extern "C" void kernel_launch(void* const* d_in, const int* in_sizes, int n_in,
                              void* d_out, int out_size, void* d_ws, size_t ws_size,
                              hipStream_t stream) {
    const float* x         = (const float*)d_in[0];
    // d_in[1] = padding_mask (unused; recomputed from lengths)
    const int*   lengths   = (const int*)d_in[2];
    const float* bos       = (const float*)d_in[3];
    const float* eos       = (const float*)d_in[4];
    const float* pos_table = (const float*)d_in[5];
    const float* ln_w      = (const float*)d_in[6];
    const float* ln_b      = (const float*)d_in[7];

    float* out_y    = (float*)d_out;
    float* out_mask = out_y + (size_t)B_ * TP2 * C_;
    float* out_len  = out_mask + (size_t)B_ * TP2;

    embed_ln_kernel<<<NBLK, 256, 0, stream>>>(
        x, lengths, bos, eos, pos_table, ln_w, ln_b,
        out_y, out_mask, out_len);
}